// Round 13
// baseline (3234.903 us; speedup 1.0000x reference)
//
#include <hip/hip_runtime.h>

#define HID   100
#define TT    1024
#define BPW   32   // batches per WG: two 16-batch halves (MFMA N=16 each)
#define WPL   8    // WGs per LSTM -> grid 24
#define NTHR  512  // 8 waves
#define NKK   4    // K = 128: 4 chunks of 32
#define CHUNK 16   // x staging chunk (steps)

typedef _Float16 f16x8 __attribute__((ext_vector_type(8)));
typedef float    f32x4 __attribute__((ext_vector_type(4)));

__device__ __forceinline__ float sigf(float x) { return 1.f / (1.f + __expf(-x)); }
__device__ __forceinline__ float tanhf_fast(float x) { return 2.f / (1.f + __expf(-2.f * x)) - 1.f; }

#define MFMA32(A, B, C) __builtin_amdgcn_mfma_f32_16x16x32_f16((A), (B), (C), 0, 0, 0)

// v12: BPW=32 (two 16-batch halves, same phase), grid 24.
// R9-R11 lesson: W residency is compiler-unwinnable; W streams from LDS
// (~100KB/step) and ~2000cyc/step of latency/barrier stall is fixed cost.
// Fix: amortize both over 2x batches -- each W fragment read once feeds
// 4 MFMAs (hi/lo x half0/half1); fixed stall paid once per 32 batches;
// 2x independent chains/wave hide each other's latency.
__global__ __launch_bounds__(NTHR, 2) void lstm3_kernel(
    const float* __restrict__ x1, const float* __restrict__ x2, const float* __restrict__ x3,
    const float* __restrict__ Wih1, const float* __restrict__ Whh1, const float* __restrict__ bi1, const float* __restrict__ bh1,
    const float* __restrict__ Wih2, const float* __restrict__ Whh2, const float* __restrict__ bi2, const float* __restrict__ bh2,
    const float* __restrict__ Wih3, const float* __restrict__ Whh3, const float* __restrict__ bi3, const float* __restrict__ bh3,
    float* __restrict__ hws)
{
    const int wg    = blockIdx.x;
    const int L     = wg / WPL;
    const int bbase = (wg % WPL) * BPW;
    const int tid   = threadIdx.x;

    const float* x   = (L == 0) ? x1   : (L == 1) ? x2   : x3;
    const float* Wih = (L == 0) ? Wih1 : (L == 1) ? Wih2 : Wih3;
    const float* Whh = (L == 0) ? Whh1 : (L == 1) ? Whh2 : Whh3;
    const float* bi  = (L == 0) ? bi1  : (L == 1) ? bi2  : bi3;
    const float* bh  = (L == 0) ? bh1  : (L == 1) ? bh2  : bh3;

    __shared__ f16x8 Wfq[25 * NKK * 64];          // 102,400 B (fragment order)
    __shared__ f16x8 hfq[2][2][2][NKK][64];       //  32,768 B [half][buf][hl][kk][lane]
    __shared__ f32x4 xch[2][CHUNK][BPW];          //  16,384 B -> total 151,552 B

    // ---- one-time W staging in fragment order (slot->k: ke = kk*32+g*8+j) ----
    for (int idx = tid; idx < 25 * NKK * 64; idx += NTHR) {
        const int l   = idx & 63;
        const int kkt = idx >> 6;
        const int kk  = kkt & 3, t = kkt >> 2;
        const int m   = l & 15, g = l >> 4;
        const int srow = (m & 3) * 100 + 4 * t + (m >> 2);
        f16x8 q;
#pragma unroll
        for (int j = 0; j < 8; ++j) {
            const int ke = kk * 32 + g * 8 + j;
            float v = 0.f;
            if (ke < 100)       v = Whh[(size_t)srow * HID + ke];
            else if (ke < 104)  v = Wih[(size_t)srow * 4 + (ke - 100)];
            else if (ke == 104) v = bi[srow] + bh[srow];
            else if (ke == 105) { const float bv = bi[srow] + bh[srow];
                                  v = bv - (float)(_Float16)bv; }
            q[j] = (_Float16)v;
        }
        Wfq[idx] = q;
    }
    // ---- h buffers zero ----
    for (int i = tid; i < 2 * 2 * 2 * NKK * 64; i += NTHR) {
        f16x8 z;
#pragma unroll
        for (int j = 0; j < 8; ++j) z[j] = (_Float16)0.f;
        ((f16x8*)hfq)[i] = z;
    }
    // ---- x chunk 0 (step-major, 16 steps x 32 batches) ----
    for (int q = tid; q < CHUNK * BPW; q += NTHR) {
        const int s = q >> 5, b = q & 31;
        xch[0][s][b] = *(const f32x4*)(x + ((size_t)(bbase + b) * TT + s) * 4);
    }
    __syncthreads();
    if (tid < 64) {  // bias ke=104,105 -> kk=3, word 16+bat, j=0,1 (hi, both halves/bufs)
        const int half = tid >> 5, buf = (tid >> 4) & 1, b = tid & 15;
        _Float16* p = (_Float16*)&hfq[half][buf][0][3][16 + b];
        p[0] = (_Float16)1.f; p[1] = (_Float16)1.f;
    }
    if (tid < 32) {  // x_0: ke=100..103 -> kk=3, word bat, j=4..7 (buf 0)
        const int b = tid, half = b >> 4, w = b & 15;
        const f32x4 xv = xch[0][0][b];
        _Float16* pH = (_Float16*)&hfq[half][0][0][3][w];
        _Float16* pL = (_Float16*)&hfq[half][0][1][3][w];
#pragma unroll
        for (int j = 0; j < 4; ++j) {
            const _Float16 hi = (_Float16)xv[j];
            pH[4 + j] = hi;
            pL[4 + j] = (_Float16)(xv[j] - (float)hi);
        }
    }
    __syncthreads();

    const int wave = tid >> 6, lane = tid & 63;
    const int bat  = lane & 15, g16 = lane >> 4;

    const int  t0 = wave, t1 = wave + 8, t2 = wave + 16;
    const bool v3 = (wave == 5);               // wave 5 also owns tile 24
    const int  t3 = 24;

    const f16x8* wp0 = &Wfq[t0 * NKK * 64 + lane];
    const f16x8* wp1 = &Wfq[t1 * NKK * 64 + lane];
    const f16x8* wp2 = &Wfq[t2 * NKK * 64 + lane];
    const f16x8* wp3 = &Wfq[t3 * NKK * 64 + lane];

    // per-tile, per-half cell state
    float ccA0 = 0.f, ccA1 = 0.f, ccA2 = 0.f, ccA3 = 0.f;
    float ccB0 = 0.f, ccB1 = 0.f, ccB2 = 0.f, ccB3 = 0.f;
    float hhA0 = 0.f, hhA1 = 0.f, hhA2 = 0.f, hhA3 = 0.f;
    float hhB0 = 0.f, hhB1 = 0.f, hhB2 = 0.f, hhB3 = 0.f;

    const int c0 = 4 * t0 + g16, c1 = 4 * t1 + g16, c2 = 4 * t2 + g16, c3 = 4 * t3 + g16;

    // one tile's 16 MFMAs: 4 chunks x (hi/lo) x (half0/half1); W read once.
#define DO_TILE(WP, AH, AL, BH, BL) do {                                      \
        const f16x8 w0_ = (WP)[0], w1_ = (WP)[64], w2_ = (WP)[128], w3_ = (WP)[192]; \
        AH = MFMA32(w0_, a0h0, AH);  AL = MFMA32(w0_, a0l0, AL);              \
        BH = MFMA32(w0_, a1h0, BH);  BL = MFMA32(w0_, a1l0, BL);              \
        AH = MFMA32(w1_, a0h1, AH);  AL = MFMA32(w1_, a0l1, AL);              \
        BH = MFMA32(w1_, a1h1, BH);  BL = MFMA32(w1_, a1l1, BL);              \
        AH = MFMA32(w2_, a0h2, AH);  AL = MFMA32(w2_, a0l2, AL);              \
        BH = MFMA32(w2_, a1h2, BH);  BL = MFMA32(w2_, a1l2, BL);              \
        AH = MFMA32(w3_, a0h3, AH);  AL = MFMA32(w3_, a0l3, AL);              \
        BH = MFMA32(w3_, a1h3, BH);  BL = MFMA32(w3_, a1l3, BL);              \
    } while (0)

#define UPDATE(AV, CC, HH, C, HALF) do {                                       \
        CC = sigf(AV[1]) * CC + sigf(AV[0]) * tanhf_fast(AV[2]);               \
        HH = sigf(AV[3]) * tanhf_fast(CC);                                     \
        const _Float16 hi_ = (_Float16)HH;                                     \
        const _Float16 lo_ = (_Float16)(HH - (float)hi_);                      \
        _Float16* pH_ = (_Float16*)&hfq[HALF][nxt][0][(C) >> 5][((((C) & 31) >> 3) << 4) + bat]; \
        _Float16* pL_ = (_Float16*)&hfq[HALF][nxt][1][(C) >> 5][((((C) & 31) >> 3) << 4) + bat]; \
        pH_[(C) & 7] = hi_; pL_[(C) & 7] = lo_;                                \
    } while (0)

#pragma unroll 1
    for (int st = 0; st < TT; ++st) {
        const int cur = st & 1, nxt = cur ^ 1;

        // h fragments, both halves: 16 x ds_read_b128
        const f16x8* h0 = &hfq[0][cur][0][0][lane];
        const f16x8* h1 = &hfq[1][cur][0][0][lane];
        const f16x8 a0h0 = h0[0],   a0h1 = h0[64],  a0h2 = h0[128], a0h3 = h0[192];
        const f16x8 a0l0 = h0[256], a0l1 = h0[320], a0l2 = h0[384], a0l3 = h0[448];
        const f16x8 a1h0 = h1[0],   a1h1 = h1[64],  a1h2 = h1[128], a1h3 = h1[192];
        const f16x8 a1l0 = h1[256], a1l1 = h1[320], a1l2 = h1[384], a1l3 = h1[448];

        f32x4 z = {0.f, 0.f, 0.f, 0.f};
        f32x4 A0h = z, A0l = z, B0h = z, B0l = z;
        f32x4 A1h = z, A1l = z, B1h = z, B1l = z;
        f32x4 A2h = z, A2l = z, B2h = z, B2l = z;

        DO_TILE(wp0, A0h, A0l, B0h, B0l);
        DO_TILE(wp1, A1h, A1l, B1h, B1l);
        DO_TILE(wp2, A2h, A2l, B2h, B2l);

        {
            const f32x4 A0 = A0h + A0l;  UPDATE(A0, ccA0, hhA0, c0, 0);
            const f32x4 B0 = B0h + B0l;  UPDATE(B0, ccB0, hhB0, c0, 1);
            const f32x4 A1 = A1h + A1l;  UPDATE(A1, ccA1, hhA1, c1, 0);
            const f32x4 B1 = B1h + B1l;  UPDATE(B1, ccB1, hhB1, c1, 1);
            const f32x4 A2 = A2h + A2l;  UPDATE(A2, ccA2, hhA2, c2, 0);
            const f32x4 B2 = B2h + B2l;  UPDATE(B2, ccB2, hhB2, c2, 1);
        }
        if (v3) {
            f32x4 A3h = z, A3l = z, B3h = z, B3l = z;
            DO_TILE(wp3, A3h, A3l, B3h, B3l);
            const f32x4 A3 = A3h + A3l;  UPDATE(A3, ccA3, hhA3, c3, 0);
            const f32x4 B3 = B3h + B3l;  UPDATE(B3, ccB3, hhB3, c3, 1);
        }

        if (wave == 7 && lane < 32) {   // x_{st+1}: ke=100..103 -> kk=3, j=4..7
            const int sp = st + 1;
            const int b = lane, half = b >> 4, w = b & 15;
            const f32x4 xv = xch[(sp >> 4) & 1][sp & (CHUNK - 1)][b];
            _Float16* pH = (_Float16*)&hfq[half][nxt][0][3][w];
            _Float16* pL = (_Float16*)&hfq[half][nxt][1][3][w];
#pragma unroll
            for (int j = 0; j < 4; ++j) {
                const _Float16 hi = (_Float16)xv[j];
                pH[4 + j] = hi;
                pL[4 + j] = (_Float16)(xv[j] - (float)hi);
            }
        }
        if (wave == 6 && (st & (CHUNK - 1)) == 0) {   // prefetch next x chunk
            const int nc = (st >> 4) + 1;
            if (nc < TT / CHUNK) {
#pragma unroll
                for (int it = 0; it < (CHUNK * BPW) / 64; ++it) {
                    const int q = it * 64 + lane;
                    const int s = q >> 5, b = q & 31;
                    xch[nc & 1][s][b] =
                        *(const f32x4*)(x + ((size_t)(bbase + b) * TT + nc * CHUNK + s) * 4);
                }
            }
        }
        __syncthreads();
    }
#undef DO_TILE
#undef UPDATE

    // ---- final h -> workspace [b_global][300], column L*100 + cell ----
    {
        const size_t obA = (size_t)(bbase + bat) * 300 + L * HID;
        const size_t obB = (size_t)(bbase + 16 + bat) * 300 + L * HID;
        hws[obA + c0] = hhA0;  hws[obB + c0] = hhB0;
        hws[obA + c1] = hhA1;  hws[obB + c1] = hhB1;
        hws[obA + c2] = hhA2;  hws[obB + c2] = hhB2;
        if (v3) { hws[obA + c3] = hhA3;  hws[obB + c3] = hhB3; }
    }
}

// out[b][o] = relu(fc_b[o] + sum_j h[b][j] * fc_W[o][j]),  j < 300, o < 12
__global__ __launch_bounds__(64, 1) void fc_kernel(
    const float* __restrict__ hws, const float* __restrict__ fcW,
    const float* __restrict__ fcb, float* __restrict__ out)
{
    const int b = blockIdx.x, lane = threadIdx.x;
    float hv[5];
#pragma unroll
    for (int c = 0; c < 5; c++) {
        const int j = lane + 64 * c;
        hv[c] = (j < 300) ? hws[b * 300 + j] : 0.f;
    }
#pragma unroll
    for (int o = 0; o < 12; o++) {
        float a = 0.f;
#pragma unroll
        for (int c = 0; c < 5; c++) {
            const int j = lane + 64 * c;
            const float wv = (j < 300) ? fcW[o * 300 + j] : 0.f;
            a += hv[c] * wv;
        }
#pragma unroll
        for (int off = 32; off > 0; off >>= 1) a += __shfl_xor(a, off, 64);
        if (lane == 0) out[b * 12 + o] = fmaxf(a + fcb[o], 0.f);
    }
}

extern "C" void kernel_launch(void* const* d_in, const int* in_sizes, int n_in,
                              void* d_out, int out_size, void* d_ws, size_t ws_size,
                              hipStream_t stream)
{
    const float* x1   = (const float*)d_in[0];
    const float* x2   = (const float*)d_in[1];
    const float* x3   = (const float*)d_in[2];
    const float* Wih1 = (const float*)d_in[3];
    const float* Whh1 = (const float*)d_in[4];
    const float* bi1  = (const float*)d_in[5];
    const float* bh1  = (const float*)d_in[6];
    const float* Wih2 = (const float*)d_in[7];
    const float* Whh2 = (const float*)d_in[8];
    const float* bi2  = (const float*)d_in[9];
    const float* bh2  = (const float*)d_in[10];
    const float* Wih3 = (const float*)d_in[11];
    const float* Whh3 = (const float*)d_in[12];
    const float* bi3  = (const float*)d_in[13];
    const float* bh3  = (const float*)d_in[14];
    const float* fcW  = (const float*)d_in[15];
    const float* fcb  = (const float*)d_in[16];

    float* hws = (float*)d_ws;  // 256*300 floats = 300 KiB

    lstm3_kernel<<<3 * WPL, NTHR, 0, stream>>>(x1, x2, x3,
                                               Wih1, Whh1, bi1, bh1,
                                               Wih2, Whh2, bi2, bh2,
                                               Wih3, Whh3, bi3, bh3, hws);
    fc_kernel<<<256, 64, 0, stream>>>(hws, fcW, fcb, (float*)d_out);
}

// Round 14
// 1425.988 us; speedup vs baseline: 2.2685x; 2.2685x over previous
//
#include <hip/hip_runtime.h>

#define HID   100
#define TT    1024
#define BPW   16   // batches per WG (= MFMA N)
#define WPL   16   // WGs per LSTM -> grid 48
#define NTHR  512  // 8 waves
#define NKK   4    // K = 128: 4 chunks of 32
#define CHUNK 64   // x staging chunk (steps)

typedef _Float16 f16x8 __attribute__((ext_vector_type(8)));
typedef float    f32x4 __attribute__((ext_vector_type(4)));

__device__ __forceinline__ float sigf(float x) { return 1.f / (1.f + __expf(-x)); }
__device__ __forceinline__ float tanhf_fast(float x) { return 2.f / (1.f + __expf(-2.f * x)) - 1.f; }

#define MFMA32(A, B, C) __builtin_amdgcn_mfma_f32_16x16x32_f16((A), (B), (C), 0, 0, 0)

// v13: R10 structure minus the lo-compensation stream.
// R12 lesson: step time ~ per-wave instr count + ~1300cyc fixed floor; BPW=16
// optimal. Error analysis: h-lo contributes ~5e-4 (same order as W's f16
// rounding, which stays); dropping h/x/bias-lo halves MFMA count and h traffic
// for a predicted absmax ~1e-3 vs threshold 2.26e-3.
// Per wave: 3 tiles (wave0: 4), 12 W-frag + 4 h-frag b128 reads, 12 MFMAs.
// One barrier/step. Wave 6: x-chunk prefetch; wave 7: x insert.
__global__ __launch_bounds__(NTHR, 2) void lstm3_kernel(
    const float* __restrict__ x1, const float* __restrict__ x2, const float* __restrict__ x3,
    const float* __restrict__ Wih1, const float* __restrict__ Whh1, const float* __restrict__ bi1, const float* __restrict__ bh1,
    const float* __restrict__ Wih2, const float* __restrict__ Whh2, const float* __restrict__ bi2, const float* __restrict__ bh2,
    const float* __restrict__ Wih3, const float* __restrict__ Whh3, const float* __restrict__ bi3, const float* __restrict__ bh3,
    float* __restrict__ hws)
{
    const int wg    = blockIdx.x;
    const int L     = wg / WPL;
    const int bbase = (wg % WPL) * BPW;
    const int tid   = threadIdx.x;

    const float* x   = (L == 0) ? x1   : (L == 1) ? x2   : x3;
    const float* Wih = (L == 0) ? Wih1 : (L == 1) ? Wih2 : Wih3;
    const float* Whh = (L == 0) ? Whh1 : (L == 1) ? Whh2 : Whh3;
    const float* bi  = (L == 0) ? bi1  : (L == 1) ? bi2  : bi3;
    const float* bh  = (L == 0) ? bh1  : (L == 1) ? bh2  : bh3;

    __shared__ f16x8 Wfq[25 * NKK * 64];      // 102,400 B (fragment order)
    __shared__ f16x8 hfq[2][NKK][64];         //   8,192 B (buf, kk, lane) -- hi only
    __shared__ f32x4 xch[2][CHUNK][BPW];      //  32,768 B -> total 143,360 B

    // ---- one-time W staging in fragment order (slot->k: ke = kk*32+g*8+j) ----
    for (int idx = tid; idx < 25 * NKK * 64; idx += NTHR) {
        const int l   = idx & 63;
        const int kkt = idx >> 6;
        const int kk  = kkt & 3, t = kkt >> 2;
        const int m   = l & 15, g = l >> 4;
        const int srow = (m & 3) * 100 + 4 * t + (m >> 2);
        f16x8 q;
#pragma unroll
        for (int j = 0; j < 8; ++j) {
            const int ke = kk * 32 + g * 8 + j;
            float v = 0.f;
            if (ke < 100)       v = Whh[(size_t)srow * HID + ke];
            else if (ke < 104)  v = Wih[(size_t)srow * 4 + (ke - 100)];
            else if (ke == 104) v = bi[srow] + bh[srow];
            q[j] = (_Float16)v;
        }
        Wfq[idx] = q;
    }
    // ---- h buffers zero ----
    for (int i = tid; i < 2 * NKK * 64; i += NTHR) {
        f16x8 z;
#pragma unroll
        for (int j = 0; j < 8; ++j) z[j] = (_Float16)0.f;
        ((f16x8*)hfq)[i] = z;
    }
    // ---- x chunk 0 (step-major) ----
    for (int q = tid; q < CHUNK * BPW; q += NTHR) {
        const int s = q >> 4, b = q & 15;
        xch[0][s][b] = *(const f32x4*)(x + ((size_t)(bbase + b) * TT + s) * 4);
    }
    __syncthreads();
    if (tid < 32) {  // bias column ke=104 -> kk=3, word 16+bat, j=0 (both bufs)
        const int buf = tid >> 4, b = tid & 15;
        ((_Float16*)&hfq[buf][3][16 + b])[0] = (_Float16)1.f;
    }
    if (tid < 16) {  // x_0: ke=100..103 -> kk=3, word bat, j=4..7 (buf 0)
        const int b = tid;
        const f32x4 xv = xch[0][0][b];
        _Float16* pH = (_Float16*)&hfq[0][3][b];
#pragma unroll
        for (int j = 0; j < 4; ++j) pH[4 + j] = (_Float16)xv[j];
    }
    __syncthreads();

    const int wave = tid >> 6, lane = tid & 63;
    const int bat  = lane & 15, g16 = lane >> 4;

    const int  t0 = wave, t1 = wave + 8, t2 = wave + 16;
    const bool v3 = (wave == 0);               // wave 0 owns tile 24
    const int  t3 = 24;

    const f16x8* wp0 = &Wfq[t0 * NKK * 64 + lane];
    const f16x8* wp1 = &Wfq[t1 * NKK * 64 + lane];
    const f16x8* wp2 = &Wfq[t2 * NKK * 64 + lane];
    const f16x8* wp3 = &Wfq[t3 * NKK * 64 + lane];

    float cc0 = 0.f, cc1 = 0.f, cc2 = 0.f, cc3 = 0.f;
    float hh0 = 0.f, hh1 = 0.f, hh2 = 0.f, hh3 = 0.f;

    const int c0 = 4 * t0 + g16, c1 = 4 * t1 + g16, c2 = 4 * t2 + g16, c3 = 4 * t3 + g16;

#define UPDATE(AV, CC, HH, C) do {                                             \
        CC = sigf(AV[1]) * CC + sigf(AV[0]) * tanhf_fast(AV[2]);               \
        HH = sigf(AV[3]) * tanhf_fast(CC);                                     \
        _Float16* pH_ = (_Float16*)&hfq[nxt][(C) >> 5][((((C) & 31) >> 3) << 4) + bat]; \
        pH_[(C) & 7] = (_Float16)HH;                                           \
    } while (0)

#pragma unroll 1
    for (int st = 0; st < TT; ++st) {
        const int cur = st & 1, nxt = cur ^ 1;

        // h fragments (hi only): 4 x ds_read_b128, shared across this wave's tiles
        const f16x8* hb = &hfq[cur][0][lane];
        const f16x8 b0 = hb[0], b1 = hb[64], b2 = hb[128], b3 = hb[192];

        f32x4 z = {0.f, 0.f, 0.f, 0.f};
        f32x4 A0 = z, A1 = z, A2 = z;

        A0 = MFMA32(wp0[0],   b0, A0);
        A1 = MFMA32(wp1[0],   b0, A1);
        A2 = MFMA32(wp2[0],   b0, A2);
        A0 = MFMA32(wp0[64],  b1, A0);
        A1 = MFMA32(wp1[64],  b1, A1);
        A2 = MFMA32(wp2[64],  b1, A2);
        A0 = MFMA32(wp0[128], b2, A0);
        A1 = MFMA32(wp1[128], b2, A1);
        A2 = MFMA32(wp2[128], b2, A2);
        A0 = MFMA32(wp0[192], b3, A0);
        A1 = MFMA32(wp1[192], b3, A1);
        A2 = MFMA32(wp2[192], b3, A2);

        UPDATE(A0, cc0, hh0, c0);
        UPDATE(A1, cc1, hh1, c1);
        UPDATE(A2, cc2, hh2, c2);
        if (v3) {
            f32x4 A3 = z;
            A3 = MFMA32(wp3[0],   b0, A3);
            A3 = MFMA32(wp3[64],  b1, A3);
            A3 = MFMA32(wp3[128], b2, A3);
            A3 = MFMA32(wp3[192], b3, A3);
            UPDATE(A3, cc3, hh3, c3);
        }

        if (wave == 7 && lane < 16) {   // x_{st+1}: ke=100..103 -> kk=3, j=4..7
            const int sp = st + 1;
            const f32x4 xv = xch[(sp >> 6) & 1][sp & (CHUNK - 1)][lane];
            _Float16* pH = (_Float16*)&hfq[nxt][3][lane];
#pragma unroll
            for (int j = 0; j < 4; ++j) pH[4 + j] = (_Float16)xv[j];
        }
        if (wave == 6 && (st & (CHUNK - 1)) == 0) {   // prefetch next x chunk
            const int nc = (st >> 6) + 1;
            if (nc < TT / CHUNK) {
#pragma unroll
                for (int it = 0; it < (CHUNK * BPW) / 64; ++it) {
                    const int q = it * 64 + lane;
                    const int s = q >> 4, b = q & 15;
                    xch[nc & 1][s][b] =
                        *(const f32x4*)(x + ((size_t)(bbase + b) * TT + nc * CHUNK + s) * 4);
                }
            }
        }
        __syncthreads();
    }
#undef UPDATE

    // ---- final h -> workspace [b_global][300], column L*100 + cell ----
    {
        const size_t ob = (size_t)(bbase + bat) * 300 + L * HID;
        hws[ob + c0] = hh0;
        hws[ob + c1] = hh1;
        hws[ob + c2] = hh2;
        if (v3) hws[ob + c3] = hh3;
    }
}

// out[b][o] = relu(fc_b[o] + sum_j h[b][j] * fc_W[o][j]),  j < 300, o < 12
__global__ __launch_bounds__(64, 1) void fc_kernel(
    const float* __restrict__ hws, const float* __restrict__ fcW,
    const float* __restrict__ fcb, float* __restrict__ out)
{
    const int b = blockIdx.x, lane = threadIdx.x;
    float hv[5];
#pragma unroll
    for (int c = 0; c < 5; c++) {
        const int j = lane + 64 * c;
        hv[c] = (j < 300) ? hws[b * 300 + j] : 0.f;
    }
#pragma unroll
    for (int o = 0; o < 12; o++) {
        float a = 0.f;
#pragma unroll
        for (int c = 0; c < 5; c++) {
            const int j = lane + 64 * c;
            const float wv = (j < 300) ? fcW[o * 300 + j] : 0.f;
            a += hv[c] * wv;
        }
#pragma unroll
        for (int off = 32; off > 0; off >>= 1) a += __shfl_xor(a, off, 64);
        if (lane == 0) out[b * 12 + o] = fmaxf(a + fcb[o], 0.f);
    }
}

extern "C" void kernel_launch(void* const* d_in, const int* in_sizes, int n_in,
                              void* d_out, int out_size, void* d_ws, size_t ws_size,
                              hipStream_t stream)
{
    const float* x1   = (const float*)d_in[0];
    const float* x2   = (const float*)d_in[1];
    const float* x3   = (const float*)d_in[2];
    const float* Wih1 = (const float*)d_in[3];
    const float* Whh1 = (const float*)d_in[4];
    const float* bi1  = (const float*)d_in[5];
    const float* bh1  = (const float*)d_in[6];
    const float* Wih2 = (const float*)d_in[7];
    const float* Whh2 = (const float*)d_in[8];
    const float* bi2  = (const float*)d_in[9];
    const float* bh2  = (const float*)d_in[10];
    const float* Wih3 = (const float*)d_in[11];
    const float* Whh3 = (const float*)d_in[12];
    const float* bi3  = (const float*)d_in[13];
    const float* bh3  = (const float*)d_in[14];
    const float* fcW  = (const float*)d_in[15];
    const float* fcb  = (const float*)d_in[16];

    float* hws = (float*)d_ws;  // 256*300 floats = 300 KiB

    lstm3_kernel<<<3 * WPL, NTHR, 0, stream>>>(x1, x2, x3,
                                               Wih1, Whh1, bi1, bh1,
                                               Wih2, Whh2, bi2, bh2,
                                               Wih3, Whh3, bi3, bh3, hws);
    fc_kernel<<<256, 64, 0, stream>>>(hws, fcW, fcb, (float*)d_out);
}

// Round 15
// 1398.043 us; speedup vs baseline: 2.3139x; 1.0200x over previous
//
#include <hip/hip_runtime.h>

#define HID   100
#define TT    1024
#define BPW   16   // batches per WG (= MFMA N)
#define WPL   16   // WGs per LSTM -> grid 48
#define NTHR  512  // 8 waves
#define NKK   4    // K = 128: 4 chunks of 32
#define CHUNK 64   // x staging chunk (steps)

typedef _Float16 f16x8 __attribute__((ext_vector_type(8)));
typedef float    f32x4 __attribute__((ext_vector_type(4)));

__device__ __forceinline__ float sigf(float x) { return 1.f / (1.f + __expf(-x)); }
__device__ __forceinline__ float tanhf_fast(float x) { return 2.f / (1.f + __expf(-2.f * x)) - 1.f; }

// v14: R13 structure; W fragments AGPR-resident via a-class end-to-end.
// R9-R13 lesson: intrinsic MFMA consumes W as v-class -> VGPR pressure ->
// allocator re-streams W from LDS (~1150 cyc/step, the largest removable
// term). Here: (1) pre-loop `"+a"` pin makes W asm-defined (non-remat) in
// AGPR class; (2) in-loop MFMA via inline asm with "a" A-operand reads the
// AGPRs directly -- no a->v copies, no VGPR pressure, AGPR file uncontended.
// s_nop x2 fences the MFMA->VALU read hazard (asm is opaque to the compiler).
__global__ __launch_bounds__(NTHR, 2) void lstm3_kernel(
    const float* __restrict__ x1, const float* __restrict__ x2, const float* __restrict__ x3,
    const float* __restrict__ Wih1, const float* __restrict__ Whh1, const float* __restrict__ bi1, const float* __restrict__ bh1,
    const float* __restrict__ Wih2, const float* __restrict__ Whh2, const float* __restrict__ bi2, const float* __restrict__ bh2,
    const float* __restrict__ Wih3, const float* __restrict__ Whh3, const float* __restrict__ bi3, const float* __restrict__ bh3,
    float* __restrict__ hws)
{
    const int wg    = blockIdx.x;
    const int L     = wg / WPL;
    const int bbase = (wg % WPL) * BPW;
    const int tid   = threadIdx.x;

    const float* x   = (L == 0) ? x1   : (L == 1) ? x2   : x3;
    const float* Wih = (L == 0) ? Wih1 : (L == 1) ? Wih2 : Wih3;
    const float* Whh = (L == 0) ? Whh1 : (L == 1) ? Whh2 : Whh3;
    const float* bi  = (L == 0) ? bi1  : (L == 1) ? bi2  : bi3;
    const float* bh  = (L == 0) ? bh1  : (L == 1) ? bh2  : bh3;

    __shared__ f16x8 Wfq[25 * NKK * 64];      // 102,400 B (fragment order)
    __shared__ f16x8 hfq[2][NKK][64];         //   8,192 B (buf, kk, lane) -- hi only
    __shared__ f32x4 xch[2][CHUNK][BPW];      //  32,768 B -> total 143,360 B

    // ---- one-time W staging in fragment order (slot->k: ke = kk*32+g*8+j) ----
    for (int idx = tid; idx < 25 * NKK * 64; idx += NTHR) {
        const int l   = idx & 63;
        const int kkt = idx >> 6;
        const int kk  = kkt & 3, t = kkt >> 2;
        const int m   = l & 15, g = l >> 4;
        const int srow = (m & 3) * 100 + 4 * t + (m >> 2);
        f16x8 q;
#pragma unroll
        for (int j = 0; j < 8; ++j) {
            const int ke = kk * 32 + g * 8 + j;
            float v = 0.f;
            if (ke < 100)       v = Whh[(size_t)srow * HID + ke];
            else if (ke < 104)  v = Wih[(size_t)srow * 4 + (ke - 100)];
            else if (ke == 104) v = bi[srow] + bh[srow];
            q[j] = (_Float16)v;
        }
        Wfq[idx] = q;
    }
    // ---- h buffers zero ----
    for (int i = tid; i < 2 * NKK * 64; i += NTHR) {
        f16x8 z;
#pragma unroll
        for (int j = 0; j < 8; ++j) z[j] = (_Float16)0.f;
        ((f16x8*)hfq)[i] = z;
    }
    // ---- x chunk 0 (step-major) ----
    for (int q = tid; q < CHUNK * BPW; q += NTHR) {
        const int s = q >> 4, b = q & 15;
        xch[0][s][b] = *(const f32x4*)(x + ((size_t)(bbase + b) * TT + s) * 4);
    }
    __syncthreads();
    if (tid < 32) {  // bias column ke=104 -> kk=3, word 16+bat, j=0 (both bufs)
        const int buf = tid >> 4, b = tid & 15;
        ((_Float16*)&hfq[buf][3][16 + b])[0] = (_Float16)1.f;
    }
    if (tid < 16) {  // x_0: ke=100..103 -> kk=3, word bat, j=4..7 (buf 0)
        const int b = tid;
        const f32x4 xv = xch[0][0][b];
        _Float16* pH = (_Float16*)&hfq[0][3][b];
#pragma unroll
        for (int j = 0; j < 4; ++j) pH[4 + j] = (_Float16)xv[j];
    }
    __syncthreads();

    const int wave = tid >> 6, lane = tid & 63;
    const int bat  = lane & 15, g16 = lane >> 4;

    const int  t0 = wave, t1 = wave + 8, t2 = wave + 16;
    const bool v3 = (wave == 0);               // wave 0 owns tile 24
    const int  t3 = 24;

    const f16x8* wp0 = &Wfq[t0 * NKK * 64 + lane];
    const f16x8* wp1 = &Wfq[t1 * NKK * 64 + lane];
    const f16x8* wp2 = &Wfq[t2 * NKK * 64 + lane];
    const f16x8* wp3 = &Wfq[t3 * NKK * 64 + lane];

    // ---- W fragments -> AGPR-resident (a-class, asm-defined -> no remat) ----
    f16x8 W00 = wp0[0], W01 = wp0[64], W02 = wp0[128], W03 = wp0[192];
    f16x8 W10 = wp1[0], W11 = wp1[64], W12 = wp1[128], W13 = wp1[192];
    f16x8 W20 = wp2[0], W21 = wp2[64], W22 = wp2[128], W23 = wp2[192];
    f16x8 W30 = wp3[0], W31 = wp3[64], W32 = wp3[128], W33 = wp3[192];
    asm volatile("" : "+a"(W00), "+a"(W01), "+a"(W02), "+a"(W03));
    asm volatile("" : "+a"(W10), "+a"(W11), "+a"(W12), "+a"(W13));
    asm volatile("" : "+a"(W20), "+a"(W21), "+a"(W22), "+a"(W23));
    asm volatile("" : "+a"(W30), "+a"(W31), "+a"(W32), "+a"(W33));

    float cc0 = 0.f, cc1 = 0.f, cc2 = 0.f, cc3 = 0.f;
    float hh0 = 0.f, hh1 = 0.f, hh2 = 0.f, hh3 = 0.f;

    const int c0 = 4 * t0 + g16, c1 = 4 * t1 + g16, c2 = 4 * t2 + g16, c3 = 4 * t3 + g16;

#define UPDATE(AV, CC, HH, C) do {                                             \
        CC = sigf(AV[1]) * CC + sigf(AV[0]) * tanhf_fast(AV[2]);               \
        HH = sigf(AV[3]) * tanhf_fast(CC);                                     \
        _Float16* pH_ = (_Float16*)&hfq[nxt][(C) >> 5][((((C) & 31) >> 3) << 4) + bat]; \
        pH_[(C) & 7] = (_Float16)HH;                                           \
    } while (0)

#pragma unroll 1
    for (int st = 0; st < TT; ++st) {
        const int cur = st & 1, nxt = cur ^ 1;

        // h fragments (hi only): 4 x ds_read_b128, shared across this wave's tiles
        const f16x8* hb = &hfq[cur][0][lane];
        const f16x8 b0 = hb[0], b1 = hb[64], b2 = hb[128], b3 = hb[192];

        f32x4 z = {0.f, 0.f, 0.f, 0.f};
        f32x4 A0 = z, A1 = z, A2 = z;

        // 12 MFMAs, kk-interleaved (3 independent acc chains), A from AGPR.
        asm volatile(
            "v_mfma_f32_16x16x32_f16 %0, %3, %15, %0\n\t"
            "v_mfma_f32_16x16x32_f16 %1, %7, %15, %1\n\t"
            "v_mfma_f32_16x16x32_f16 %2, %11, %15, %2\n\t"
            "v_mfma_f32_16x16x32_f16 %0, %4, %16, %0\n\t"
            "v_mfma_f32_16x16x32_f16 %1, %8, %16, %1\n\t"
            "v_mfma_f32_16x16x32_f16 %2, %12, %16, %2\n\t"
            "v_mfma_f32_16x16x32_f16 %0, %5, %17, %0\n\t"
            "v_mfma_f32_16x16x32_f16 %1, %9, %17, %1\n\t"
            "v_mfma_f32_16x16x32_f16 %2, %13, %17, %2\n\t"
            "v_mfma_f32_16x16x32_f16 %0, %6, %18, %0\n\t"
            "v_mfma_f32_16x16x32_f16 %1, %10, %18, %1\n\t"
            "v_mfma_f32_16x16x32_f16 %2, %14, %18, %2\n\t"
            "s_nop 7\n\t"
            "s_nop 7"
            : "+v"(A0), "+v"(A1), "+v"(A2)
            : "a"(W00), "a"(W01), "a"(W02), "a"(W03),
              "a"(W10), "a"(W11), "a"(W12), "a"(W13),
              "a"(W20), "a"(W21), "a"(W22), "a"(W23),
              "v"(b0), "v"(b1), "v"(b2), "v"(b3));

        UPDATE(A0, cc0, hh0, c0);
        UPDATE(A1, cc1, hh1, c1);
        UPDATE(A2, cc2, hh2, c2);
        if (v3) {
            f32x4 A3 = z;
            asm volatile(
                "v_mfma_f32_16x16x32_f16 %0, %1, %5, %0\n\t"
                "v_mfma_f32_16x16x32_f16 %0, %2, %6, %0\n\t"
                "v_mfma_f32_16x16x32_f16 %0, %3, %7, %0\n\t"
                "v_mfma_f32_16x16x32_f16 %0, %4, %8, %0\n\t"
                "s_nop 7\n\t"
                "s_nop 7"
                : "+v"(A3)
                : "a"(W30), "a"(W31), "a"(W32), "a"(W33),
                  "v"(b0), "v"(b1), "v"(b2), "v"(b3));
            UPDATE(A3, cc3, hh3, c3);
        }

        if (wave == 7 && lane < 16) {   // x_{st+1}: ke=100..103 -> kk=3, j=4..7
            const int sp = st + 1;
            const f32x4 xv = xch[(sp >> 6) & 1][sp & (CHUNK - 1)][lane];
            _Float16* pH = (_Float16*)&hfq[nxt][3][lane];
#pragma unroll
            for (int j = 0; j < 4; ++j) pH[4 + j] = (_Float16)xv[j];
        }
        if (wave == 6 && (st & (CHUNK - 1)) == 0) {   // prefetch next x chunk
            const int nc = (st >> 6) + 1;
            if (nc < TT / CHUNK) {
#pragma unroll
                for (int it = 0; it < (CHUNK * BPW) / 64; ++it) {
                    const int q = it * 64 + lane;
                    const int s = q >> 4, b = q & 15;
                    xch[nc & 1][s][b] =
                        *(const f32x4*)(x + ((size_t)(bbase + b) * TT + nc * CHUNK + s) * 4);
                }
            }
        }
        __syncthreads();
    }
#undef UPDATE

    // ---- final h -> workspace [b_global][300], column L*100 + cell ----
    {
        const size_t ob = (size_t)(bbase + bat) * 300 + L * HID;
        hws[ob + c0] = hh0;
        hws[ob + c1] = hh1;
        hws[ob + c2] = hh2;
        if (v3) hws[ob + c3] = hh3;
    }
}

// out[b][o] = relu(fc_b[o] + sum_j h[b][j] * fc_W[o][j]),  j < 300, o < 12
__global__ __launch_bounds__(64, 1) void fc_kernel(
    const float* __restrict__ hws, const float* __restrict__ fcW,
    const float* __restrict__ fcb, float* __restrict__ out)
{
    const int b = blockIdx.x, lane = threadIdx.x;
    float hv[5];
#pragma unroll
    for (int c = 0; c < 5; c++) {
        const int j = lane + 64 * c;
        hv[c] = (j < 300) ? hws[b * 300 + j] : 0.f;
    }
#pragma unroll
    for (int o = 0; o < 12; o++) {
        float a = 0.f;
#pragma unroll
        for (int c = 0; c < 5; c++) {
            const int j = lane + 64 * c;
            const float wv = (j < 300) ? fcW[o * 300 + j] : 0.f;
            a += hv[c] * wv;
        }
#pragma unroll
        for (int off = 32; off > 0; off >>= 1) a += __shfl_xor(a, off, 64);
        if (lane == 0) out[b * 12 + o] = fmaxf(a + fcb[o], 0.f);
    }
}

extern "C" void kernel_launch(void* const* d_in, const int* in_sizes, int n_in,
                              void* d_out, int out_size, void* d_ws, size_t ws_size,
                              hipStream_t stream)
{
    const float* x1   = (const float*)d_in[0];
    const float* x2   = (const float*)d_in[1];
    const float* x3   = (const float*)d_in[2];
    const float* Wih1 = (const float*)d_in[3];
    const float* Whh1 = (const float*)d_in[4];
    const float* bi1  = (const float*)d_in[5];
    const float* bh1  = (const float*)d_in[6];
    const float* Wih2 = (const float*)d_in[7];
    const float* Whh2 = (const float*)d_in[8];
    const float* bi2  = (const float*)d_in[9];
    const float* bh2  = (const float*)d_in[10];
    const float* Wih3 = (const float*)d_in[11];
    const float* Whh3 = (const float*)d_in[12];
    const float* bi3  = (const float*)d_in[13];
    const float* bh3  = (const float*)d_in[14];
    const float* fcW  = (const float*)d_in[15];
    const float* fcb  = (const float*)d_in[16];

    float* hws = (float*)d_ws;  // 256*300 floats = 300 KiB

    lstm3_kernel<<<3 * WPL, NTHR, 0, stream>>>(x1, x2, x3,
                                               Wih1, Whh1, bi1, bh1,
                                               Wih2, Whh2, bi2, bh2,
                                               Wih3, Whh3, bi3, bh3, hws);
    fc_kernel<<<256, 64, 0, stream>>>(hws, fcW, fcb, (float*)d_out);
}

// Round 16
// 776.375 us; speedup vs baseline: 4.1667x; 1.8007x over previous
//
#include <hip/hip_runtime.h>

#define HID   100
#define TT    1024
#define BPW   16   // batches per WG (= MFMA N)
#define WPL   16   // WGs per LSTM -> grid 48
#define NTHR  512  // 8 waves
#define NKK   4    // K = 128: 4 chunks of 32
#define CHUNK 64   // x staging chunk (steps)

typedef _Float16 f16x8 __attribute__((ext_vector_type(8)));
typedef float    f32x4 __attribute__((ext_vector_type(4)));

#if __has_builtin(__builtin_amdgcn_exp2f)
#define EXP2(x) __builtin_amdgcn_exp2f(x)
#else
#define EXP2(x) exp2f(x)
#endif
#if __has_builtin(__builtin_amdgcn_rcpf)
#define RCP(x) __builtin_amdgcn_rcpf(x)
#else
#define RCP(x) (1.f / (x))
#endif

#define MFMA32(A, B, C) __builtin_amdgcn_mfma_f32_16x16x32_f16((A), (B), (C), 0, 0, 0)

// v15: R13 verified structure; cut per-wave instructions.
//  - Scale folded into W at staging: rows i,f,o x -log2e, g-rows x -2log2e
//    -> sigma = rcp(1+exp2(A)) directly from MFMA output (saves 4 mul/cell).
//  - Raw v_exp/v_rcp (no div refinement): rcp err ~1e-7 << 4.9e-4 budget.
//  - Step loop unrolled x2: parity-constant h-read bases and per-cell write
//    pointers hoisted out of the loop (no nxt pointer math per step).
//  - Intrinsic MFMAs (compiler interleaves ds_read/MFMA with fine lgkmcnt).
__global__ __launch_bounds__(NTHR, 2) void lstm3_kernel(
    const float* __restrict__ x1, const float* __restrict__ x2, const float* __restrict__ x3,
    const float* __restrict__ Wih1, const float* __restrict__ Whh1, const float* __restrict__ bi1, const float* __restrict__ bh1,
    const float* __restrict__ Wih2, const float* __restrict__ Whh2, const float* __restrict__ bi2, const float* __restrict__ bh2,
    const float* __restrict__ Wih3, const float* __restrict__ Whh3, const float* __restrict__ bi3, const float* __restrict__ bh3,
    float* __restrict__ hws)
{
    const int wg    = blockIdx.x;
    const int L     = wg / WPL;
    const int bbase = (wg % WPL) * BPW;
    const int tid   = threadIdx.x;

    const float* x   = (L == 0) ? x1   : (L == 1) ? x2   : x3;
    const float* Wih = (L == 0) ? Wih1 : (L == 1) ? Wih2 : Wih3;
    const float* Whh = (L == 0) ? Whh1 : (L == 1) ? Whh2 : Whh3;
    const float* bi  = (L == 0) ? bi1  : (L == 1) ? bi2  : bi3;
    const float* bh  = (L == 0) ? bh1  : (L == 1) ? bh2  : bh3;

    __shared__ f16x8 Wfq[25 * NKK * 64];      // 102,400 B (fragment order, pre-scaled)
    __shared__ f16x8 hfq[2][NKK][64];         //   8,192 B (buf, kk, lane)
    __shared__ f32x4 xch[2][CHUNK][BPW];      //  32,768 B -> total 143,360 B

    // ---- one-time W staging, fragment order, scale folded ----
    for (int idx = tid; idx < 25 * NKK * 64; idx += NTHR) {
        const int l   = idx & 63;
        const int kkt = idx >> 6;
        const int kk  = kkt & 3, t = kkt >> 2;
        const int m   = l & 15, g = l >> 4;
        const int gate = m & 3;
        const int srow = gate * 100 + 4 * t + (m >> 2);
        const float scl = (gate == 2) ? -2.885390082f : -1.442695041f;
        f16x8 q;
#pragma unroll
        for (int j = 0; j < 8; ++j) {
            const int ke = kk * 32 + g * 8 + j;
            float v = 0.f;
            if (ke < 100)       v = Whh[(size_t)srow * HID + ke];
            else if (ke < 104)  v = Wih[(size_t)srow * 4 + (ke - 100)];
            else if (ke == 104) v = bi[srow] + bh[srow];
            q[j] = (_Float16)(v * scl);
        }
        Wfq[idx] = q;
    }
    // ---- h buffers zero ----
    for (int i = tid; i < 2 * NKK * 64; i += NTHR) {
        f16x8 z;
#pragma unroll
        for (int j = 0; j < 8; ++j) z[j] = (_Float16)0.f;
        ((f16x8*)hfq)[i] = z;
    }
    // ---- x chunk 0 (step-major) ----
    for (int q = tid; q < CHUNK * BPW; q += NTHR) {
        const int s = q >> 4, b = q & 15;
        xch[0][s][b] = *(const f32x4*)(x + ((size_t)(bbase + b) * TT + s) * 4);
    }
    __syncthreads();
    if (tid < 32) {  // bias column ke=104 -> kk=3, word 16+bat, j=0 (both bufs)
        const int buf = tid >> 4, b = tid & 15;
        ((_Float16*)&hfq[buf][3][16 + b])[0] = (_Float16)1.f;
    }
    if (tid < 16) {  // x_0: ke=100..103 -> kk=3, word bat, j=4..7 (buf 0)
        const int b = tid;
        const f32x4 xv = xch[0][0][b];
        _Float16* pH = (_Float16*)&hfq[0][3][b];
#pragma unroll
        for (int j = 0; j < 4; ++j) pH[4 + j] = (_Float16)xv[j];
    }
    __syncthreads();

    const int wave = tid >> 6, lane = tid & 63;
    const int bat  = lane & 15, g16 = lane >> 4;

    const int  t0 = wave, t1 = wave + 8, t2 = wave + 16;
    const bool v3 = (wave == 0);
    const int  t3 = 24;

    const f16x8* wp0 = &Wfq[t0 * NKK * 64 + lane];
    const f16x8* wp1 = &Wfq[t1 * NKK * 64 + lane];
    const f16x8* wp2 = &Wfq[t2 * NKK * 64 + lane];
    const f16x8* wp3 = &Wfq[t3 * NKK * 64 + lane];

    float cc0 = 0.f, cc1 = 0.f, cc2 = 0.f, cc3 = 0.f;
    float hh0 = 0.f, hh1 = 0.f, hh2 = 0.f, hh3 = 0.f;

    const int c0 = 4 * t0 + g16, c1 = 4 * t1 + g16, c2 = 4 * t2 + g16, c3 = 4 * t3 + g16;

    // hoisted, parity-constant pointers
    char* const hbase = (char*)hfq;
#define CELL_OFF(C) ((size_t)(((C) >> 5) * 1024 + (((((C) & 31) >> 3) << 4) + bat) * 16 + ((C) & 7) * 2))
    _Float16* const p0E = (_Float16*)(hbase + 4096 + CELL_OFF(c0));  // even step writes buf1
    _Float16* const p1E = (_Float16*)(hbase + 4096 + CELL_OFF(c1));
    _Float16* const p2E = (_Float16*)(hbase + 4096 + CELL_OFF(c2));
    _Float16* const p3E = (_Float16*)(hbase + 4096 + CELL_OFF(c3));
    _Float16* const p0O = (_Float16*)(hbase + CELL_OFF(c0));         // odd step writes buf0
    _Float16* const p1O = (_Float16*)(hbase + CELL_OFF(c1));
    _Float16* const p2O = (_Float16*)(hbase + CELL_OFF(c2));
    _Float16* const p3O = (_Float16*)(hbase + CELL_OFF(c3));
#undef CELL_OFF
    const f16x8* const hbE = &hfq[0][0][lane];   // even step reads buf0
    const f16x8* const hbO = &hfq[1][0][lane];   // odd step reads buf1
    _Float16* const xiE = (_Float16*)(hbase + 4096 + 3 * 1024 + lane * 16);  // x-insert even -> buf1
    _Float16* const xiO = (_Float16*)(hbase + 3 * 1024 + lane * 16);         // x-insert odd  -> buf0

#define UPDATE(AV, CC, HH, PH) do {                                          \
        const float si = RCP(1.f + EXP2(AV[0]));                             \
        const float sf = RCP(1.f + EXP2(AV[1]));                             \
        const float tg = 2.f * RCP(1.f + EXP2(AV[2])) - 1.f;                 \
        const float so = RCP(1.f + EXP2(AV[3]));                             \
        CC = sf * CC + si * tg;                                              \
        const float tc = 2.f * RCP(1.f + EXP2(CC * -2.885390082f)) - 1.f;    \
        HH = so * tc;                                                        \
        *(PH) = (_Float16)HH;                                                \
    } while (0)

#define STEP_BODY(HB, P0, P1, P2, P3, XI, ST) do {                           \
        const f16x8 b0 = (HB)[0], b1 = (HB)[64], b2 = (HB)[128], b3 = (HB)[192]; \
        f32x4 z = {0.f, 0.f, 0.f, 0.f};                                      \
        f32x4 A0 = z, A1 = z, A2 = z;                                        \
        A0 = MFMA32(wp0[0],   b0, A0);                                       \
        A1 = MFMA32(wp1[0],   b0, A1);                                       \
        A2 = MFMA32(wp2[0],   b0, A2);                                       \
        A0 = MFMA32(wp0[64],  b1, A0);                                       \
        A1 = MFMA32(wp1[64],  b1, A1);                                       \
        A2 = MFMA32(wp2[64],  b1, A2);                                       \
        A0 = MFMA32(wp0[128], b2, A0);                                       \
        A1 = MFMA32(wp1[128], b2, A1);                                       \
        A2 = MFMA32(wp2[128], b2, A2);                                       \
        A0 = MFMA32(wp0[192], b3, A0);                                       \
        A1 = MFMA32(wp1[192], b3, A1);                                       \
        A2 = MFMA32(wp2[192], b3, A2);                                       \
        UPDATE(A0, cc0, hh0, P0);                                            \
        UPDATE(A1, cc1, hh1, P1);                                            \
        UPDATE(A2, cc2, hh2, P2);                                            \
        if (v3) {                                                            \
            f32x4 A3 = z;                                                    \
            A3 = MFMA32(wp3[0],   b0, A3);                                   \
            A3 = MFMA32(wp3[64],  b1, A3);                                   \
            A3 = MFMA32(wp3[128], b2, A3);                                   \
            A3 = MFMA32(wp3[192], b3, A3);                                   \
            UPDATE(A3, cc3, hh3, P3);                                        \
        }                                                                    \
        if (wave == 7 && lane < 16) {                                        \
            const int sp = (ST) + 1;                                         \
            const f32x4 xv = xch[(sp >> 6) & 1][sp & (CHUNK - 1)][lane];     \
            _Float16* pX = (XI);                                             \
            pX[4] = (_Float16)xv[0]; pX[5] = (_Float16)xv[1];                \
            pX[6] = (_Float16)xv[2]; pX[7] = (_Float16)xv[3];                \
        }                                                                    \
    } while (0)

#pragma unroll 1
    for (int st = 0; st < TT; st += 2) {
        // even step: read buf0, write buf1
        STEP_BODY(hbE, p0E, p1E, p2E, p3E, xiE, st);
        if (wave == 6 && (st & (CHUNK - 1)) == 0) {   // prefetch next x chunk
            const int nc = (st >> 6) + 1;
            if (nc < TT / CHUNK) {
#pragma unroll
                for (int it = 0; it < (CHUNK * BPW) / 64; ++it) {
                    const int q = it * 64 + lane;
                    const int s = q >> 4, b = q & 15;
                    xch[nc & 1][s][b] =
                        *(const f32x4*)(x + ((size_t)(bbase + b) * TT + nc * CHUNK + s) * 4);
                }
            }
        }
        __syncthreads();
        // odd step: read buf1, write buf0
        STEP_BODY(hbO, p0O, p1O, p2O, p3O, xiO, st + 1);
        __syncthreads();
    }
#undef STEP_BODY
#undef UPDATE

    // ---- final h -> workspace [b_global][300], column L*100 + cell ----
    {
        const size_t ob = (size_t)(bbase + bat) * 300 + L * HID;
        hws[ob + c0] = hh0;
        hws[ob + c1] = hh1;
        hws[ob + c2] = hh2;
        if (v3) hws[ob + c3] = hh3;
    }
}

// out[b][o] = relu(fc_b[o] + sum_j h[b][j] * fc_W[o][j]),  j < 300, o < 12
__global__ __launch_bounds__(64, 1) void fc_kernel(
    const float* __restrict__ hws, const float* __restrict__ fcW,
    const float* __restrict__ fcb, float* __restrict__ out)
{
    const int b = blockIdx.x, lane = threadIdx.x;
    float hv[5];
#pragma unroll
    for (int c = 0; c < 5; c++) {
        const int j = lane + 64 * c;
        hv[c] = (j < 300) ? hws[b * 300 + j] : 0.f;
    }
#pragma unroll
    for (int o = 0; o < 12; o++) {
        float a = 0.f;
#pragma unroll
        for (int c = 0; c < 5; c++) {
            const int j = lane + 64 * c;
            const float wv = (j < 300) ? fcW[o * 300 + j] : 0.f;
            a += hv[c] * wv;
        }
#pragma unroll
        for (int off = 32; off > 0; off >>= 1) a += __shfl_xor(a, off, 64);
        if (lane == 0) out[b * 12 + o] = fmaxf(a + fcb[o], 0.f);
    }
}

extern "C" void kernel_launch(void* const* d_in, const int* in_sizes, int n_in,
                              void* d_out, int out_size, void* d_ws, size_t ws_size,
                              hipStream_t stream)
{
    const float* x1   = (const float*)d_in[0];
    const float* x2   = (const float*)d_in[1];
    const float* x3   = (const float*)d_in[2];
    const float* Wih1 = (const float*)d_in[3];
    const float* Whh1 = (const float*)d_in[4];
    const float* bi1  = (const float*)d_in[5];
    const float* bh1  = (const float*)d_in[6];
    const float* Wih2 = (const float*)d_in[7];
    const float* Whh2 = (const float*)d_in[8];
    const float* bi2  = (const float*)d_in[9];
    const float* bh2  = (const float*)d_in[10];
    const float* Wih3 = (const float*)d_in[11];
    const float* Whh3 = (const float*)d_in[12];
    const float* bi3  = (const float*)d_in[13];
    const float* bh3  = (const float*)d_in[14];
    const float* fcW  = (const float*)d_in[15];
    const float* fcb  = (const float*)d_in[16];

    float* hws = (float*)d_ws;  // 256*300 floats = 300 KiB

    lstm3_kernel<<<3 * WPL, NTHR, 0, stream>>>(x1, x2, x3,
                                               Wih1, Whh1, bi1, bh1,
                                               Wih2, Whh2, bi2, bh2,
                                               Wih3, Whh3, bi3, bh3, hws);
    fc_kernel<<<256, 64, 0, stream>>>(hws, fcW, fcb, (float*)d_out);
}

// Round 19
// 723.039 us; speedup vs baseline: 4.4740x; 1.0738x over previous
//
#include <hip/hip_runtime.h>

#define HID   100
#define TT    1024
#define BPW   16   // batches per WG (= MFMA N)
#define WPL   16   // WGs per LSTM -> grid 48
#define NTHR  512  // 8 waves
#define NKK   4    // K = 128: 4 chunks of 32
#define CHUNK 64   // x staging chunk (steps)

typedef _Float16 f16x8 __attribute__((ext_vector_type(8)));
typedef float    f32x4 __attribute__((ext_vector_type(4)));

#if __has_builtin(__builtin_amdgcn_exp2f)
#define EXP2(x) __builtin_amdgcn_exp2f(x)
#else
#define EXP2(x) exp2f(x)
#endif
#if __has_builtin(__builtin_amdgcn_rcpf)
#define RCP(x) __builtin_amdgcn_rcpf(x)
#else
#define RCP(x) (1.f / (x))
#endif

// v18 = v17 + s_nop 2 at the HEAD of each MFMA asm block.
// R17 failure diagnosis: CDNA hazard -- VALU write (acc zero-init v_mov, and
// v_accvgpr_write copies for the "a" input constraints) immediately followed
// by MFMA reading those regs needs ~2 wait states; intrinsics get them
// auto-inserted, inline asm doesn't. R14 passed on scheduling luck; R15's
// leaner VALU removed the accidental separation. s_nop 2 (3 cyc) at block
// head covers SrcA/B/C read-after-VALU-write; tail already has 2x s_nop 7.
// W stays in compiler-TRACKED AGPRs ("+a" pins, no clobbers -> no parking).
__global__ __launch_bounds__(NTHR, 2) void lstm3_kernel(
    const float* __restrict__ x1, const float* __restrict__ x2, const float* __restrict__ x3,
    const float* __restrict__ Wih1, const float* __restrict__ Whh1, const float* __restrict__ bi1, const float* __restrict__ bh1,
    const float* __restrict__ Wih2, const float* __restrict__ Whh2, const float* __restrict__ bi2, const float* __restrict__ bh2,
    const float* __restrict__ Wih3, const float* __restrict__ Whh3, const float* __restrict__ bi3, const float* __restrict__ bh3,
    float* __restrict__ hws)
{
    const int wg    = blockIdx.x;
    const int L     = wg / WPL;
    const int bbase = (wg % WPL) * BPW;
    const int tid   = threadIdx.x;

    const float* x   = (L == 0) ? x1   : (L == 1) ? x2   : x3;
    const float* Wih = (L == 0) ? Wih1 : (L == 1) ? Wih2 : Wih3;
    const float* Whh = (L == 0) ? Whh1 : (L == 1) ? Whh2 : Whh3;
    const float* bi  = (L == 0) ? bi1  : (L == 1) ? bi2  : bi3;
    const float* bh  = (L == 0) ? bh1  : (L == 1) ? bh2  : bh3;

    __shared__ f16x8 Wfq[25 * NKK * 64];      // 102,400 B (staging; cold after init)
    __shared__ f16x8 hfq[2][NKK][64];         //   8,192 B (buf, kk, lane)
    __shared__ f32x4 xch[2][CHUNK][BPW];      //  32,768 B -> total 143,360 B

    // ---- one-time W staging, fragment order, exp2-scale folded ----
    for (int idx = tid; idx < 25 * NKK * 64; idx += NTHR) {
        const int l   = idx & 63;
        const int kkt = idx >> 6;
        const int kk  = kkt & 3, t = kkt >> 2;
        const int m   = l & 15, g = l >> 4;
        const int gate = m & 3;
        const int srow = gate * 100 + 4 * t + (m >> 2);
        const float scl = (gate == 2) ? -2.885390082f : -1.442695041f;
        f16x8 q;
#pragma unroll
        for (int j = 0; j < 8; ++j) {
            const int ke = kk * 32 + g * 8 + j;
            float v = 0.f;
            if (ke < 100)       v = Whh[(size_t)srow * HID + ke];
            else if (ke < 104)  v = Wih[(size_t)srow * 4 + (ke - 100)];
            else if (ke == 104) v = bi[srow] + bh[srow];
            q[j] = (_Float16)(v * scl);
        }
        Wfq[idx] = q;
    }
    // ---- h buffers zero ----
    for (int i = tid; i < 2 * NKK * 64; i += NTHR) {
        f16x8 z;
#pragma unroll
        for (int j = 0; j < 8; ++j) z[j] = (_Float16)0.f;
        ((f16x8*)hfq)[i] = z;
    }
    // ---- x chunk 0 (step-major) ----
    for (int q = tid; q < CHUNK * BPW; q += NTHR) {
        const int s = q >> 4, b = q & 15;
        xch[0][s][b] = *(const f32x4*)(x + ((size_t)(bbase + b) * TT + s) * 4);
    }
    __syncthreads();
    if (tid < 32) {  // bias column ke=104 -> kk=3, word 16+bat, j=0 (both bufs)
        const int buf = tid >> 4, b = tid & 15;
        ((_Float16*)&hfq[buf][3][16 + b])[0] = (_Float16)1.f;
    }
    if (tid < 16) {  // x_0: ke=100..103 -> kk=3, word bat, j=4..7 (buf 0)
        const int b = tid;
        const f32x4 xv = xch[0][0][b];
        _Float16* pH = (_Float16*)&hfq[0][3][b];
#pragma unroll
        for (int j = 0; j < 4; ++j) pH[4 + j] = (_Float16)xv[j];
    }
    __syncthreads();

    const int wave = tid >> 6, lane = tid & 63;
    const int bat  = lane & 15, g16 = lane >> 4;

    const int  t0 = wave, t1 = wave + 8, t2 = wave + 16;
    const bool v3 = (wave == 0);
    const int  t3 = 24;

    // ---- W fragments -> compiler-tracked AGPR residents ----
    const f16x8* wp0 = &Wfq[t0 * NKK * 64 + lane];
    const f16x8* wp1 = &Wfq[t1 * NKK * 64 + lane];
    const f16x8* wp2 = &Wfq[t2 * NKK * 64 + lane];
    const f16x8* wp3 = &Wfq[t3 * NKK * 64 + lane];
    f16x8 W00 = wp0[0], W01 = wp0[64], W02 = wp0[128], W03 = wp0[192];
    f16x8 W10 = wp1[0], W11 = wp1[64], W12 = wp1[128], W13 = wp1[192];
    f16x8 W20 = wp2[0], W21 = wp2[64], W22 = wp2[128], W23 = wp2[192];
    f16x8 W30 = wp3[0], W31 = wp3[64], W32 = wp3[128], W33 = wp3[192];
    asm volatile("" : "+a"(W00), "+a"(W01), "+a"(W02), "+a"(W03));
    asm volatile("" : "+a"(W10), "+a"(W11), "+a"(W12), "+a"(W13));
    asm volatile("" : "+a"(W20), "+a"(W21), "+a"(W22), "+a"(W23));
    asm volatile("" : "+a"(W30), "+a"(W31), "+a"(W32), "+a"(W33));

    float cc0 = 0.f, cc1 = 0.f, cc2 = 0.f, cc3 = 0.f;
    float hh0 = 0.f, hh1 = 0.f, hh2 = 0.f, hh3 = 0.f;

    const int c0 = 4 * t0 + g16, c1 = 4 * t1 + g16, c2 = 4 * t2 + g16, c3 = 4 * t3 + g16;

    // hoisted, parity-constant pointers
    char* const hbase = (char*)hfq;
#define CELL_OFF(C) ((size_t)(((C) >> 5) * 1024 + (((((C) & 31) >> 3) << 4) + bat) * 16 + ((C) & 7) * 2))
    _Float16* const p0E = (_Float16*)(hbase + 4096 + CELL_OFF(c0));  // even step writes buf1
    _Float16* const p1E = (_Float16*)(hbase + 4096 + CELL_OFF(c1));
    _Float16* const p2E = (_Float16*)(hbase + 4096 + CELL_OFF(c2));
    _Float16* const p3E = (_Float16*)(hbase + 4096 + CELL_OFF(c3));
    _Float16* const p0O = (_Float16*)(hbase + CELL_OFF(c0));         // odd step writes buf0
    _Float16* const p1O = (_Float16*)(hbase + CELL_OFF(c1));
    _Float16* const p2O = (_Float16*)(hbase + CELL_OFF(c2));
    _Float16* const p3O = (_Float16*)(hbase + CELL_OFF(c3));
#undef CELL_OFF
    const f16x8* const hbE = &hfq[0][0][lane];   // even step reads buf0
    const f16x8* const hbO = &hfq[1][0][lane];   // odd step reads buf1
    _Float16* const xiE = (_Float16*)(hbase + 4096 + 3 * 1024 + lane * 16);  // x-insert even -> buf1
    _Float16* const xiO = (_Float16*)(hbase + 3 * 1024 + lane * 16);         // x-insert odd  -> buf0

#define UPDATE(AV, CC, HH, PH) do {                                          \
        const float si = RCP(1.f + EXP2(AV[0]));                             \
        const float sf = RCP(1.f + EXP2(AV[1]));                             \
        const float tg = 2.f * RCP(1.f + EXP2(AV[2])) - 1.f;                 \
        const float so = RCP(1.f + EXP2(AV[3]));                             \
        CC = sf * CC + si * tg;                                              \
        const float tc = 2.f * RCP(1.f + EXP2(CC * -2.885390082f)) - 1.f;    \
        HH = so * tc;                                                        \
        *(PH) = (_Float16)HH;                                                \
    } while (0)

#define STEP_BODY(HB, P0, P1, P2, P3, XI, ST) do {                           \
        const f16x8 b0 = (HB)[0], b1 = (HB)[64], b2 = (HB)[128], b3 = (HB)[192]; \
        f32x4 z = {0.f, 0.f, 0.f, 0.f};                                      \
        f32x4 A0 = z, A1 = z, A2 = z;                                        \
        asm volatile(                                                        \
            "s_nop 2\n\t"                                                    \
            "v_mfma_f32_16x16x32_f16 %0, %7, %3, %0\n\t"                     \
            "v_mfma_f32_16x16x32_f16 %1, %11, %3, %1\n\t"                    \
            "v_mfma_f32_16x16x32_f16 %2, %15, %3, %2\n\t"                    \
            "v_mfma_f32_16x16x32_f16 %0, %8, %4, %0\n\t"                     \
            "v_mfma_f32_16x16x32_f16 %1, %12, %4, %1\n\t"                    \
            "v_mfma_f32_16x16x32_f16 %2, %16, %4, %2\n\t"                    \
            "v_mfma_f32_16x16x32_f16 %0, %9, %5, %0\n\t"                     \
            "v_mfma_f32_16x16x32_f16 %1, %13, %5, %1\n\t"                    \
            "v_mfma_f32_16x16x32_f16 %2, %17, %5, %2\n\t"                    \
            "v_mfma_f32_16x16x32_f16 %0, %10, %6, %0\n\t"                    \
            "v_mfma_f32_16x16x32_f16 %1, %14, %6, %1\n\t"                    \
            "v_mfma_f32_16x16x32_f16 %2, %18, %6, %2\n\t"                    \
            "s_nop 7\n\t"                                                    \
            "s_nop 7"                                                        \
            : "+v"(A0), "+v"(A1), "+v"(A2)                                   \
            : "v"(b0), "v"(b1), "v"(b2), "v"(b3),                            \
              "a"(W00), "a"(W01), "a"(W02), "a"(W03),                        \
              "a"(W10), "a"(W11), "a"(W12), "a"(W13),                        \
              "a"(W20), "a"(W21), "a"(W22), "a"(W23));                       \
        UPDATE(A0, cc0, hh0, P0);                                            \
        UPDATE(A1, cc1, hh1, P1);                                            \
        UPDATE(A2, cc2, hh2, P2);                                            \
        if (v3) {                                                            \
            f32x4 A3 = z;                                                    \
            asm volatile(                                                    \
                "s_nop 2\n\t"                                                \
                "v_mfma_f32_16x16x32_f16 %0, %5, %1, %0\n\t"                 \
                "v_mfma_f32_16x16x32_f16 %0, %6, %2, %0\n\t"                 \
                "v_mfma_f32_16x16x32_f16 %0, %7, %3, %0\n\t"                 \
                "v_mfma_f32_16x16x32_f16 %0, %8, %4, %0\n\t"                 \
                "s_nop 7\n\t"                                                \
                "s_nop 7"                                                    \
                : "+v"(A3)                                                   \
                : "v"(b0), "v"(b1), "v"(b2), "v"(b3),                        \
                  "a"(W30), "a"(W31), "a"(W32), "a"(W33));                   \
            UPDATE(A3, cc3, hh3, P3);                                        \
        }                                                                    \
        if (wave == 7 && lane < 16) {                                        \
            const int sp = (ST) + 1;                                         \
            const f32x4 xv = xch[(sp >> 6) & 1][sp & (CHUNK - 1)][lane];     \
            _Float16* pX = (XI);                                             \
            pX[4] = (_Float16)xv[0]; pX[5] = (_Float16)xv[1];                \
            pX[6] = (_Float16)xv[2]; pX[7] = (_Float16)xv[3];                \
        }                                                                    \
    } while (0)

#pragma unroll 1
    for (int st = 0; st < TT; st += 2) {
        // even step: read buf0, write buf1
        STEP_BODY(hbE, p0E, p1E, p2E, p3E, xiE, st);
        if (wave == 6 && (st & (CHUNK - 1)) == 0) {   // prefetch next x chunk
            const int nc = (st >> 6) + 1;
            if (nc < TT / CHUNK) {
#pragma unroll
                for (int it = 0; it < (CHUNK * BPW) / 64; ++it) {
                    const int q = it * 64 + lane;
                    const int s = q >> 4, b = q & 15;
                    xch[nc & 1][s][b] =
                        *(const f32x4*)(x + ((size_t)(bbase + b) * TT + nc * CHUNK + s) * 4);
                }
            }
        }
        __syncthreads();
        // odd step: read buf1, write buf0
        STEP_BODY(hbO, p0O, p1O, p2O, p3O, xiO, st + 1);
        __syncthreads();
    }
#undef STEP_BODY
#undef UPDATE

    // ---- final h -> workspace [b_global][300], column L*100 + cell ----
    {
        const size_t ob = (size_t)(bbase + bat) * 300 + L * HID;
        hws[ob + c0] = hh0;
        hws[ob + c1] = hh1;
        hws[ob + c2] = hh2;
        if (v3) hws[ob + c3] = hh3;
    }
}

// out[b][o] = relu(fc_b[o] + sum_j h[b][j] * fc_W[o][j]),  j < 300, o < 12
__global__ __launch_bounds__(64, 1) void fc_kernel(
    const float* __restrict__ hws, const float* __restrict__ fcW,
    const float* __restrict__ fcb, float* __restrict__ out)
{
    const int b = blockIdx.x, lane = threadIdx.x;
    float hv[5];
#pragma unroll
    for (int c = 0; c < 5; c++) {
        const int j = lane + 64 * c;
        hv[c] = (j < 300) ? hws[b * 300 + j] : 0.f;
    }
#pragma unroll
    for (int o = 0; o < 12; o++) {
        float a = 0.f;
#pragma unroll
        for (int c = 0; c < 5; c++) {
            const int j = lane + 64 * c;
            const float wv = (j < 300) ? fcW[o * 300 + j] : 0.f;
            a += hv[c] * wv;
        }
#pragma unroll
        for (int off = 32; off > 0; off >>= 1) a += __shfl_xor(a, off, 64);
        if (lane == 0) out[b * 12 + o] = fmaxf(a + fcb[o], 0.f);
    }
}

extern "C" void kernel_launch(void* const* d_in, const int* in_sizes, int n_in,
                              void* d_out, int out_size, void* d_ws, size_t ws_size,
                              hipStream_t stream)
{
    const float* x1   = (const float*)d_in[0];
    const float* x2   = (const float*)d_in[1];
    const float* x3   = (const float*)d_in[2];
    const float* Wih1 = (const float*)d_in[3];
    const float* Whh1 = (const float*)d_in[4];
    const float* bi1  = (const float*)d_in[5];
    const float* bh1  = (const float*)d_in[6];
    const float* Wih2 = (const float*)d_in[7];
    const float* Whh2 = (const float*)d_in[8];
    const float* bi2  = (const float*)d_in[9];
    const float* bh2  = (const float*)d_in[10];
    const float* Wih3 = (const float*)d_in[11];
    const float* Whh3 = (const float*)d_in[12];
    const float* bi3  = (const float*)d_in[13];
    const float* bh3  = (const float*)d_in[14];
    const float* fcW  = (const float*)d_in[15];
    const float* fcb  = (const float*)d_in[16];

    float* hws = (float*)d_ws;  // 256*300 floats = 300 KiB

    lstm3_kernel<<<3 * WPL, NTHR, 0, stream>>>(x1, x2, x3,
                                               Wih1, Whh1, bi1, bh1,
                                               Wih2, Whh2, bi2, bh2,
                                               Wih3, Whh3, bi3, bh3, hws);
    fc_kernel<<<256, 64, 0, stream>>>(hws, fcW, fcb, (float*)d_out);
}